// Round 1
// baseline (176.294 us; speedup 1.0000x reference)
//
#include <hip/hip_runtime.h>

// Problem: B=2, D=64, N=512, H=256, OUT=64
// mid[b] = sum_{c,i} relu( relu(hi[b,i]+hc[b,c]+b1) @ w2 + b2 ) @ w3 + N^2*b3
// out = relu(mid @ w4 + b4) @ w5 + b5

using f32x4  = __attribute__((ext_vector_type(4))) float;
using short8 = __attribute__((ext_vector_type(8))) short;

__device__ __forceinline__ short f2bf(float f) {
    unsigned u = __float_as_uint(f);
    unsigned r = u + 0x7FFFu + ((u >> 16) & 1u);   // RNE
    return (short)(r >> 16);
}

// ---- prep1: hi[b,n,h] = sum_d x[b,d,n]*w1[d,h]; hcb = sum_d x*w1[64+d,h] + b1[h]
__global__ __launch_bounds__(256) void prep1(const float* __restrict__ in,
                                             const float* __restrict__ w1,
                                             const float* __restrict__ b1,
                                             float* __restrict__ hi,
                                             float* __restrict__ hcb) {
    int tid = threadIdx.x;
    int b = blockIdx.x >> 9, n = blockIdx.x & 511;
    __shared__ float xs[64];
    if (tid < 64) xs[tid] = in[(size_t)(b * 64 + tid) * 512 + n];
    __syncthreads();
    float a0 = 0.f, a1 = 0.f;
#pragma unroll 8
    for (int d = 0; d < 64; ++d) {
        float xv = xs[d];
        a0 += xv * w1[d * 256 + tid];
        a1 += xv * w1[(64 + d) * 256 + tid];
    }
    size_t o = (size_t)(b * 512 + n) * 256 + tid;
    hi[o]  = a0;
    hcb[o] = a1 + b1[tid];
}

// ---- prep2: w2t[n,k] = bf16(w2[k,n])
__global__ __launch_bounds__(256) void prep2(const float* __restrict__ w2,
                                             short* __restrict__ w2t) {
    int idx = blockIdx.x * 256 + threadIdx.x;
    int n = idx & 255, k = idx >> 8;
    w2t[n * 256 + k] = f2bf(w2[k * 256 + n]);
}

// ---- big: per block, 64 pairs (8 c x 8 i); A=relu(hi+hcb) in LDS (XOR swizzled);
//      GEMM [64x256]x[256x256] via mfma 16x16x32 bf16; epilogue relu(+b2), row-sum -> partials
__global__ __launch_bounds__(256) void big(const float* __restrict__ hi,
                                           const float* __restrict__ hcb,
                                           const short* __restrict__ w2t,
                                           const float* __restrict__ b2,
                                           float* __restrict__ partials) {
    __shared__ short8 tA[64 * 32];           // 64 rows x 32 chunks(16B) = 32 KB
    short* tAe = (short*)tA;
    int tid = threadIdx.x;
    int bid = blockIdx.x;
    int b = bid >> 12, rem = bid & 4095, cc = rem >> 6, ic = rem & 63;

    const float* hib  = hi  + (size_t)b * 512 * 256;
    const float* hcbb = hcb + (size_t)b * 512 * 256;

    float hv[8], cv[8];
#pragma unroll
    for (int j = 0; j < 8; ++j) hv[j] = hib[(size_t)(ic * 8 + j) * 256 + tid];
#pragma unroll
    for (int j = 0; j < 8; ++j) cv[j] = hcbb[(size_t)(cc * 8 + j) * 256 + tid];

#pragma unroll
    for (int p = 0; p < 64; ++p) {
        float t = hv[p & 7] + cv[p >> 3];
        t = t > 0.f ? t : 0.f;
        tAe[p * 256 + (tid ^ ((p & 7) << 3))] = f2bf(t);   // chunk-XOR swizzle
    }
    __syncthreads();

    int lane = tid & 63, wid = tid >> 6;
    int colbase = wid * 64;
    int lr = lane & 15, lg = lane >> 4;

    f32x4 acc[4][4] = {};
#pragma unroll
    for (int kk = 0; kk < 8; ++kk) {
        short8 af[4], bfr[4];
#pragma unroll
        for (int r = 0; r < 4; ++r) {
            int row = r * 16 + lr;
            int kc  = kk * 4 + lg;
            af[r] = tA[row * 32 + (kc ^ (row & 7))];
        }
#pragma unroll
        for (int cf = 0; cf < 4; ++cf) {
            int n = colbase + cf * 16 + lr;
            bfr[cf] = *reinterpret_cast<const short8*>(&w2t[n * 256 + kk * 32 + lg * 8]);
        }
#pragma unroll
        for (int r = 0; r < 4; ++r)
#pragma unroll
            for (int cf = 0; cf < 4; ++cf)
                acc[r][cf] = __builtin_amdgcn_mfma_f32_16x16x32_bf16(af[r], bfr[cf], acc[r][cf], 0, 0, 0);
    }

    // epilogue: u = relu(acc + b2[col]); sum over the 64 rows of this block
#pragma unroll
    for (int cf = 0; cf < 4; ++cf) {
        int col = colbase + cf * 16 + lr;
        float b2v = b2[col];
        float s = 0.f;
#pragma unroll
        for (int r = 0; r < 4; ++r)
#pragma unroll
            for (int j = 0; j < 4; ++j) {
                float u = acc[r][cf][j] + b2v;
                s += u > 0.f ? u : 0.f;
            }
        s += __shfl_xor(s, 16);
        s += __shfl_xor(s, 32);
        if (lg == 0) partials[(size_t)bid * 256 + col] = s;
    }
}

// ---- reduce: 128 blocks, each sums 64 partial rows
__global__ __launch_bounds__(256) void reduceK(const float* __restrict__ partials,
                                               float* __restrict__ stage2) {
    int tid = threadIdx.x, blk = blockIdx.x;
    size_t base = (size_t)blk * 64 * 256;
    float s = 0.f;
#pragma unroll 8
    for (int r = 0; r < 64; ++r) s += partials[base + (size_t)r * 256 + tid];
    stage2[blk * 256 + tid] = s;
}

// ---- final tail MLP (tiny)
__global__ __launch_bounds__(256) void finalK(const float* __restrict__ stage2,
                                              const float* __restrict__ w3,
                                              const float* __restrict__ b3,
                                              const float* __restrict__ w4,
                                              const float* __restrict__ b4,
                                              const float* __restrict__ w5,
                                              const float* __restrict__ b5,
                                              float* __restrict__ out) {
    __shared__ float su[256], mid[256], o[256];
    int tid = threadIdx.x;
    for (int b = 0; b < 2; ++b) {
        float s = 0.f;
        for (int r = 0; r < 64; ++r) s += stage2[(size_t)(b * 64 + r) * 256 + tid];
        su[tid] = s;
        __syncthreads();
        float m = 262144.0f * b3[tid];
        for (int k = 0; k < 256; ++k) m += su[k] * w3[k * 256 + tid];
        mid[tid] = m;
        __syncthreads();
        float ov = b4[tid];
        for (int k = 0; k < 256; ++k) ov += mid[k] * w4[k * 256 + tid];
        o[tid] = ov > 0.f ? ov : 0.f;
        __syncthreads();
        if (tid < 64) {
            float r = b5[tid];
            for (int k = 0; k < 256; ++k) r += o[k] * w5[k * 64 + tid];
            out[b * 64 + tid] = r;
        }
        __syncthreads();
    }
}

extern "C" void kernel_launch(void* const* d_in, const int* in_sizes, int n_in,
                              void* d_out, int out_size, void* d_ws, size_t ws_size,
                              hipStream_t stream) {
    const float* in = (const float*)d_in[0];
    const float* w1 = (const float*)d_in[1];
    const float* b1 = (const float*)d_in[2];
    const float* w2 = (const float*)d_in[3];
    const float* b2 = (const float*)d_in[4];
    const float* w3 = (const float*)d_in[5];
    const float* b3 = (const float*)d_in[6];
    const float* w4 = (const float*)d_in[7];
    const float* b4 = (const float*)d_in[8];
    const float* w5 = (const float*)d_in[9];
    const float* b5 = (const float*)d_in[10];
    float* out = (float*)d_out;

    char* ws = (char*)d_ws;
    float* hi       = (float*)(ws);                         // 1 MB
    float* hcb      = (float*)(ws + (1u << 20));            // 1 MB
    short* w2t      = (short*)(ws + (2u << 20));            // 128 KB
    float* partials = (float*)(ws + (2u << 20) + (1u << 18)); // 8 MB
    float* stage2   = (float*)(ws + (2u << 20) + (1u << 18) + (8u << 20)); // 128 KB

    prep1<<<1024, 256, 0, stream>>>(in, w1, b1, hi, hcb);
    prep2<<<256, 256, 0, stream>>>(w2, w2t);
    big<<<8192, 256, 0, stream>>>(hi, hcb, w2t, b2, partials);
    reduceK<<<128, 256, 0, stream>>>(partials, stage2);
    finalK<<<1, 256, 0, stream>>>(stage2, w3, b3, w4, b4, w5, b5, out);
}

// Round 2
// 115.176 us; speedup vs baseline: 1.5307x; 1.5307x over previous
//
#include <hip/hip_runtime.h>

// B=2, D=64, N=512, H=256, OUT=64
// mid[b] = sum_{c,i} relu( relu(hi[b,i]+hc[b,c]+b1) @ w2 + b2 ) @ w3 + N^2*b3
// out = relu(mid @ w4 + b4) @ w5 + b5

using f32x16  = __attribute__((ext_vector_type(16))) float;
using short8  = __attribute__((ext_vector_type(8))) short;
using float2v = __attribute__((ext_vector_type(2))) float;

__device__ __forceinline__ short f2bf(float f) {
    unsigned u = __float_as_uint(f);
    unsigned r = u + 0x7FFFu + ((u >> 16) & 1u);   // RNE
    return (short)(r >> 16);
}

// ---- prep1: hi[b,n,h] = sum_d x[b,d,n]*w1[d,h]; hcb = sum_d x*w1[64+d,h] + b1[h]
__global__ __launch_bounds__(256) void prep1(const float* __restrict__ in,
                                             const float* __restrict__ w1,
                                             const float* __restrict__ b1,
                                             float* __restrict__ hi,
                                             float* __restrict__ hcb) {
    int tid = threadIdx.x;
    int b = blockIdx.x >> 9, n = blockIdx.x & 511;
    __shared__ float xs[64];
    if (tid < 64) xs[tid] = in[(size_t)(b * 64 + tid) * 512 + n];
    __syncthreads();
    float a0 = 0.f, a1 = 0.f;
#pragma unroll 8
    for (int d = 0; d < 64; ++d) {
        float xv = xs[d];
        a0 += xv * w1[d * 256 + tid];
        a1 += xv * w1[(64 + d) * 256 + tid];
    }
    size_t o = (size_t)(b * 512 + n) * 256 + tid;
    hi[o]  = a0;
    hcb[o] = a1 + b1[tid];
}

// ---- prep2: w2t[n,k] = bf16(w2[k,n])
__global__ __launch_bounds__(256) void prep2(const float* __restrict__ w2,
                                             short* __restrict__ w2t) {
    int idx = blockIdx.x * 256 + threadIdx.x;
    int n = idx & 255, k = idx >> 8;
    w2t[n * 256 + k] = f2bf(w2[k * 256 + n]);
}

// ---- big (v2): 512 persistent blocks, 16 tiles each. Per tile: 64 pairs x 256 cols.
// B (w2t) held in VGPRs per wave; A generated packed into double-buffered LDS;
// mfma 32x32x16 bf16; per-tile relu(+b2) row-sum accumulated in registers.
__global__ __launch_bounds__(256, 2) void big(const float* __restrict__ hi,
                                              const float* __restrict__ hcb,
                                              const short* __restrict__ w2t,
                                              const float* __restrict__ b2,
                                              float* __restrict__ partials) {
    __shared__ __align__(16) unsigned tA[2][64 * 128];   // 2 x 32 KB

    const int tid = threadIdx.x;
    const int bid = blockIdx.x;                 // [0,512)
    const int b   = bid >> 8, rem = bid & 255;
    const int cc  = rem >> 2, icg = rem & 3;    // block owns cc (8 c-rows), 16 ic tiles

    const float* __restrict__ hib  = hi  + (size_t)b * (512 * 256);
    const float* __restrict__ hcbb = hcb + (size_t)b * (512 * 256);

    const int cp   = tid & 127, half = tid >> 7;   // A-gen mapping
    const int lane = tid & 63,  wid  = tid >> 6;   // MFMA mapping
    const int h    = lane >> 5, l31  = lane & 31, l7 = lane & 7;
    const int colbase = wid * 64;

    // context rows (fixed for the whole block)
    float2v cv2[4];
#pragma unroll
    for (int j = 0; j < 4; ++j)
        cv2[j] = *reinterpret_cast<const float2v*>(
            &hcbb[(size_t)(cc * 8 + half * 4 + j) * 256 + 2 * cp]);

    // persistent B fragments: 64 cols x K=256 bf16 per wave = 128 VGPRs
    short8 bfr[2][16];
    const short8* w2v = reinterpret_cast<const short8*>(w2t);
#pragma unroll
    for (int cf = 0; cf < 2; ++cf)
#pragma unroll
        for (int kk = 0; kk < 16; ++kk)
            bfr[cf][kk] = w2v[(size_t)(colbase + cf * 32 + l31) * 32 + kk * 2 + h];

    const float b2v0 = b2[colbase + l31];
    const float b2v1 = b2[colbase + 32 + l31];
    float psum0 = 0.f, psum1 = 0.f;

    const int cbase = cp >> 2, woff = cp & 3;

    auto gen = [&](int ic, unsigned* __restrict__ buf) {
        float2v hv2[8];
#pragma unroll
        for (int j = 0; j < 8; ++j)
            hv2[j] = *reinterpret_cast<const float2v*>(
                &hib[(size_t)(ic * 8 + j) * 256 + 2 * cp]);
#pragma unroll
        for (int p = 0; p < 32; ++p) {
            float ax = hv2[p & 7][0] + cv2[p >> 3][0];
            float ay = hv2[p & 7][1] + cv2[p >> 3][1];
            ax = fmaxf(ax, 0.f);
            ay = fmaxf(ay, 0.f);
            unsigned pk;
            asm("v_cvt_pk_bf16_f32 %0, %1, %2" : "=v"(pk) : "v"(ax), "v"(ay));
            // row = half*32+p; 16B-chunk XOR swizzle keyed on row&7 (= p&7)
            buf[(half * 32 + p) * 128 + (((cbase ^ (p & 7)) << 2) + woff)] = pk;
        }
    };

    gen(icg * 16, tA[0]);
    __syncthreads();

#pragma unroll 2
    for (int t = 0; t < 16; ++t) {
        const int cur = t & 1;
        if (t < 15) gen(icg * 16 + t + 1, tA[cur ^ 1]);   // overlaps MFMA below

        const short8* tAv = reinterpret_cast<const short8*>(tA[cur]);
        f32x16 acc00 = {}, acc01 = {}, acc10 = {}, acc11 = {};
#pragma unroll
        for (int kk = 0; kk < 16; ++kk) {
            const int sc = (kk * 2 + h) ^ l7;          // swizzled 16B chunk
            short8 a0 = tAv[l31 * 32 + sc];
            short8 a1 = tAv[(32 + l31) * 32 + sc];
            acc00 = __builtin_amdgcn_mfma_f32_32x32x16_bf16(a0, bfr[0][kk], acc00, 0, 0, 0);
            acc01 = __builtin_amdgcn_mfma_f32_32x32x16_bf16(a0, bfr[1][kk], acc01, 0, 0, 0);
            acc10 = __builtin_amdgcn_mfma_f32_32x32x16_bf16(a1, bfr[0][kk], acc10, 0, 0, 0);
            acc11 = __builtin_amdgcn_mfma_f32_32x32x16_bf16(a1, bfr[1][kk], acc11, 0, 0, 0);
        }
        float s0 = 0.f, s1 = 0.f;
#pragma unroll
        for (int e = 0; e < 16; ++e) {
            s0 += fmaxf(acc00[e] + b2v0, 0.f);
            s0 += fmaxf(acc10[e] + b2v0, 0.f);
            s1 += fmaxf(acc01[e] + b2v1, 0.f);
            s1 += fmaxf(acc11[e] + b2v1, 0.f);
        }
        psum0 += s0;
        psum1 += s1;
        __syncthreads();
    }

    psum0 += __shfl_xor(psum0, 32);
    psum1 += __shfl_xor(psum1, 32);
    if (h == 0) {
        partials[(size_t)bid * 256 + colbase + l31]      = psum0;
        partials[(size_t)bid * 256 + colbase + 32 + l31] = psum1;
    }
}

// ---- final tail: sum 256 partial rows per batch, then tiny MLP chain
__global__ __launch_bounds__(256) void finalK(const float* __restrict__ partials,
                                              const float* __restrict__ w3,
                                              const float* __restrict__ b3,
                                              const float* __restrict__ w4,
                                              const float* __restrict__ b4,
                                              const float* __restrict__ w5,
                                              const float* __restrict__ b5,
                                              float* __restrict__ out) {
    __shared__ float su[256], mid[256], o[256];
    int tid = threadIdx.x;
    for (int b = 0; b < 2; ++b) {
        const float* pb = partials + (size_t)b * 256 * 256;
        float s = 0.f;
#pragma unroll 8
        for (int r = 0; r < 256; ++r) s += pb[(size_t)r * 256 + tid];
        su[tid] = s;
        __syncthreads();
        float m = 262144.0f * b3[tid];
        for (int k = 0; k < 256; ++k) m += su[k] * w3[k * 256 + tid];
        mid[tid] = m;
        __syncthreads();
        float ov = b4[tid];
        for (int k = 0; k < 256; ++k) ov += mid[k] * w4[k * 256 + tid];
        o[tid] = fmaxf(ov, 0.f);
        __syncthreads();
        if (tid < 64) {
            float r = b5[tid];
            for (int k = 0; k < 256; ++k) r += o[k] * w5[k * 64 + tid];
            out[b * 64 + tid] = r;
        }
        __syncthreads();
    }
}

extern "C" void kernel_launch(void* const* d_in, const int* in_sizes, int n_in,
                              void* d_out, int out_size, void* d_ws, size_t ws_size,
                              hipStream_t stream) {
    const float* in = (const float*)d_in[0];
    const float* w1 = (const float*)d_in[1];
    const float* b1 = (const float*)d_in[2];
    const float* w2 = (const float*)d_in[3];
    const float* b2 = (const float*)d_in[4];
    const float* w3 = (const float*)d_in[5];
    const float* b3 = (const float*)d_in[6];
    const float* w4 = (const float*)d_in[7];
    const float* b4 = (const float*)d_in[8];
    const float* w5 = (const float*)d_in[9];
    const float* b5 = (const float*)d_in[10];
    float* out = (float*)d_out;

    char* ws = (char*)d_ws;
    float* hi       = (float*)(ws);                                   // 1 MB
    float* hcb      = (float*)(ws + (1u << 20));                      // 1 MB
    short* w2t      = (short*)(ws + (2u << 20));                      // 128 KB
    float* partials = (float*)(ws + (2u << 20) + (1u << 18));         // 512 KB

    prep1<<<1024, 256, 0, stream>>>(in, w1, b1, hi, hcb);
    prep2<<<256, 256, 0, stream>>>(w2, w2t);
    big<<<512, 256, 0, stream>>>(hi, hcb, w2t, b2, partials);
    finalK<<<1, 256, 0, stream>>>(partials, w3, b3, w4, b4, w5, b5, out);
}